// Round 1
// 373.979 us; speedup vs baseline: 1.0669x; 1.0669x over previous
//
#include <hip/hip_runtime.h>
#include <hip/hip_bf16.h>
#include <math.h>

// Problem constants (FavorPlusAttention): B=2, T=4096, d=1024, h=16, dk=64, m=256
#define BB 2
#define TT 4096
#define DD 1024
#define NH 16
#define DK 64
#define MM 256
#define BT (BB*TT)        // 8192 rows
#define FEPS 1e-6f

typedef _Float16 f16x8 __attribute__((ext_vector_type(8)));
using f32x4 = __attribute__((ext_vector_type(4))) float;

#define GL2LDS16(g, l) __builtin_amdgcn_global_load_lds( \
    (const __attribute__((address_space(1))) void*)(g), \
    (__attribute__((address_space(3))) void*)(l), 16, 0, 0)

static __device__ __forceinline__ unsigned short f16bits(_Float16 v) {
    union { _Float16 f; unsigned short u; } c; c.f = v; return c.u;
}

// ---------------------------------------------------------------------------
// hi/lo fp16 split: src [rows][1024] fp32 -> dst [rows][2048] f16 = [hi|lo]
// ---------------------------------------------------------------------------
__global__ __launch_bounds__(256) void split_hl(const float* __restrict__ src,
                                                unsigned short* __restrict__ dst)
{
    const int r = blockIdx.x;
    const int c = threadIdx.x * 4;
    float4 v = *(const float4*)(src + (size_t)r * 1024 + c);
    float f[4] = {v.x, v.y, v.z, v.w};
    union { _Float16 h[4]; uint2 u; } hv, lv;
#pragma unroll
    for (int i = 0; i < 4; i++) {
        hv.h[i] = (_Float16)f[i];
        lv.h[i] = (_Float16)(f[i] - (float)hv.h[i]);
    }
    unsigned short* d = dst + (size_t)r * 2048;
    *(uint2*)(d + c)        = hv.u;
    *(uint2*)(d + 1024 + c) = lv.u;
}

// hi-only fp16 weight cast: 3 weights -> [3][1024][1024] f16 (B-operand).
__global__ __launch_bounds__(256) void split_w3h(const float* __restrict__ W0,
                                                 const float* __restrict__ W1,
                                                 const float* __restrict__ W2,
                                                 unsigned short* __restrict__ dst)
{
    const int r = blockIdx.x;            // 0..3071
    const int wi = r >> 10, rr = r & 1023;
    const float* W = (wi == 0) ? W0 : (wi == 1) ? W1 : W2;
    const int c = threadIdx.x * 4;
    float4 v = *(const float4*)(W + (size_t)rr * 1024 + c);
    float f[4] = {v.x, v.y, v.z, v.w};
    union { _Float16 h[4]; uint2 u; } hv;
#pragma unroll
    for (int i = 0; i < 4; i++) hv.h[i] = (_Float16)f[i];
    *(uint2*)(dst + (size_t)r * 1024 + c) = hv.u;
}

// ---------------------------------------------------------------------------
// gemm_pipe: 256x128 tile, 8-wave (2Mx4N), BK=64, counted-vmcnt pipelined
// split-fp16 GEMM (T2 swizzle + T3/T4 phased counted-vmcnt + T5 setprio).
// C = scale*(A@B^T)(+bias). A: [8192][2048] f16 [hi|lo], B: [1024][1024] f16.
// K' = 2048 = 32 K-tiles of 64. Per wave 128x32 output: acc[8][2] f32x4.
// LDS 96KB: A dbuf 2 x (2 halves x [128][64]) + B dbuf 2 x [128][64], u16,
// XOR-swizzled (chunk16 ^= row&7) with pre-swizzled global source (rule 21).
// Pipeline: A staged 1 K-tile ahead (issued phase 0; A regions are read
// through phase 1, so dbuf caps A at 1-ahead), B staged 2 ahead. One
// s_waitcnt vmcnt(2) per K-tile. Raw s_barrier only (no vmcnt(0) drain).
// Per-thread queue: enter tile t with B(t+1)[2] outstanding; P0 +A(t+1)[4];
// P1 +B(t+2)[2]; vmcnt(2) -> exactly tile t+1 landed. Every gl2lds issue is
// >=1 barrier after the last ds_read of its destination region.
// ---------------------------------------------------------------------------
__global__ __launch_bounds__(512, 2) void gemm_pipe(
    const unsigned short* __restrict__ A,
    const unsigned short* __restrict__ B0, const unsigned short* __restrict__ B1,
    const unsigned short* __restrict__ B2,
    float* __restrict__ C0, float* __restrict__ C1, float* __restrict__ C2,
    const float* __restrict__ bias,
    float sc0, float sc1, float sc2)
{
    extern __shared__ char smem[];   // 98304 B
    // byte offsets: A(buf,half) = buf*32768 + half*16384 ; B(buf) = 65536 + buf*16384

    const int which = blockIdx.x >> 3;
    const int col0 = (blockIdx.x & 7) * 128;
    const int row0 = blockIdx.y * 256;
    const unsigned short* Bp = (which == 0) ? B0 : (which == 1) ? B1 : B2;
    float* Cp = (which == 0) ? C0 : (which == 1) ? C1 : C2;
    const float scl = (which == 0) ? sc0 : (which == 1) ? sc1 : sc2;

    const int tid = threadIdx.x;             // 0..511
    const int w = tid >> 6, lane = tid & 63;
    const int wm = w >> 2, wn = w & 3;       // 2M x 4N wave grid

    // ---- staging addressing: 2 x 16B per thread per 128x64 half-tile ----
    // slot s -> (row = s>>3, chunk16 = s&7); source chunk pre-swizzled.
    const int s0 = tid, s1 = 512 + tid;
    const int r0 = s0 >> 3, c0s = (s0 & 7) ^ (r0 & 7);
    const int r1 = s1 >> 3, c1s = (s1 & 7) ^ (r1 & 7);
    const size_t aG0 = (size_t)(row0 + r0) * 2048 + c0s * 8;
    const size_t aG1 = (size_t)(row0 + r1) * 2048 + c1s * 8;
    const size_t bG0 = (size_t)(col0 + r0) * 1024 + c0s * 8;
    const size_t bG1 = (size_t)(col0 + r1) * 1024 + c1s * 8;
    const int ldD0 = (0 * 512 + w * 64) * 16;   // wave-uniform LDS dest bases
    const int ldD1 = (1 * 512 + w * 64) * 16;

    auto stA = [&](int buf, int kt) {           // both A halves: 4 loads/thread
        const size_t ka = (size_t)kt * 64;      // hi|lo planes are contiguous in A
        char* d0 = smem + buf * 32768;
        char* d1 = d0 + 16384;
        GL2LDS16(A + aG0 + ka, d0 + ldD0);
        GL2LDS16(A + aG1 + ka, d0 + ldD1);
        GL2LDS16(A + aG0 + 128 * 2048 + ka, d1 + ldD0);
        GL2LDS16(A + aG1 + 128 * 2048 + ka, d1 + ldD1);
    };
    auto stB = [&](int buf, int kt) {           // 2 loads/thread
        const size_t kb = (size_t)(kt & 15) * 64;   // B re-read for hi and lo pass
        char* d = smem + 65536 + buf * 16384;
        GL2LDS16(Bp + bG0 + kb, d + ldD0);
        GL2LDS16(Bp + bG1 + kb, d + ldD1);
    };

    // ---- ds_read fragment addressing (swizzled) ----
    const int swz = lane & 7;                   // == row&7 for all frag rows
    const int acg = lane >> 4;                  // k chunk group
    const int kc0 = ((acg + 0) ^ swz) * 16;     // ks=0 chunk byte offset
    const int kc1 = ((acg + 4) ^ swz) * 16;     // ks=1
    const char* aBaseT = smem + wm * 16384 + (lane & 15) * 128;            // + buf*32768 + mf*2048 + kc
    const char* bBaseT = smem + 65536 + (wn * 32 + (lane & 15)) * 128;     // + buf*16384 + nf*2048 + kc

    f32x4 acc[8][2];
#pragma unroll
    for (int i = 0; i < 8; i++)
#pragma unroll
        for (int j = 0; j < 2; j++) acc[i][j] = (f32x4){0.f, 0.f, 0.f, 0.f};
    f16x8 af[4][2], bfr[2][2];

    // ---- prologue: queue = B(0)[2], A(0)[4], B(1)[2]; vmcnt(2) -> tile 0 in ----
    stB(0, 0);
    stA(0, 0);
    stB(1, 1);
    asm volatile("s_waitcnt vmcnt(2)" ::: "memory");
    __builtin_amdgcn_s_barrier();

#pragma unroll 2
    for (int t = 0; t < 32; ++t) {
        const int buf = t & 1;
        const int abase = buf * 32768;
        const int bbase = buf * 16384;
        // ================= phase 0: stage A(t+1); read A(mf0..3)+B; MFMA rq=0
        stA(buf ^ 1, (t + 1 < 32) ? t + 1 : 0);
#pragma unroll
        for (int mf = 0; mf < 4; ++mf) {
            af[mf][0] = *(const f16x8*)(aBaseT + abase + mf * 2048 + kc0);
            af[mf][1] = *(const f16x8*)(aBaseT + abase + mf * 2048 + kc1);
        }
#pragma unroll
        for (int nf = 0; nf < 2; ++nf) {
            bfr[nf][0] = *(const f16x8*)(bBaseT + bbase + nf * 2048 + kc0);
            bfr[nf][1] = *(const f16x8*)(bBaseT + bbase + nf * 2048 + kc1);
        }
        __builtin_amdgcn_s_barrier();
        asm volatile("s_waitcnt lgkmcnt(0)" ::: "memory");
        __builtin_amdgcn_sched_barrier(0);
        __builtin_amdgcn_s_setprio(1);
#pragma unroll
        for (int mf = 0; mf < 4; ++mf)
#pragma unroll
            for (int nf = 0; nf < 2; ++nf) {
                acc[mf][nf] = __builtin_amdgcn_mfma_f32_16x16x32_f16(
                    af[mf][0], bfr[nf][0], acc[mf][nf], 0, 0, 0);
                acc[mf][nf] = __builtin_amdgcn_mfma_f32_16x16x32_f16(
                    af[mf][1], bfr[nf][1], acc[mf][nf], 0, 0, 0);
            }
        __builtin_amdgcn_s_setprio(0);
        __builtin_amdgcn_s_barrier();
        // ================= phase 1: stage B(t+2); read A(mf4..7); vmcnt; MFMA rq=1
        stB(buf, (t + 2 < 32) ? t + 2 : 0);
#pragma unroll
        for (int mf = 0; mf < 4; ++mf) {
            af[mf][0] = *(const f16x8*)(aBaseT + abase + (mf + 4) * 2048 + kc0);
            af[mf][1] = *(const f16x8*)(aBaseT + abase + (mf + 4) * 2048 + kc1);
        }
        asm volatile("s_waitcnt vmcnt(2)" ::: "memory");
        __builtin_amdgcn_s_barrier();
        asm volatile("s_waitcnt lgkmcnt(0)" ::: "memory");
        __builtin_amdgcn_sched_barrier(0);
        __builtin_amdgcn_s_setprio(1);
#pragma unroll
        for (int mf = 0; mf < 4; ++mf)
#pragma unroll
            for (int nf = 0; nf < 2; ++nf) {
                acc[mf + 4][nf] = __builtin_amdgcn_mfma_f32_16x16x32_f16(
                    af[mf][0], bfr[nf][0], acc[mf + 4][nf], 0, 0, 0);
                acc[mf + 4][nf] = __builtin_amdgcn_mfma_f32_16x16x32_f16(
                    af[mf][1], bfr[nf][1], acc[mf + 4][nf], 0, 0, 0);
            }
        __builtin_amdgcn_s_setprio(0);
        __builtin_amdgcn_s_barrier();
    }
    asm volatile("s_waitcnt vmcnt(0)" ::: "memory");   // drain tail junk loads

    // ---- epilogue: C/D layout col = lane&15, row = (lane>>4)*4 + reg  [m89]
    float bv[2];
#pragma unroll
    for (int nf = 0; nf < 2; ++nf) {
        int gcol = col0 + wn * 32 + nf * 16 + (lane & 15);
        bv[nf] = bias ? bias[gcol] : 0.f;
    }
#pragma unroll
    for (int mf = 0; mf < 8; ++mf) {
        const int grow = row0 + wm * 128 + mf * 16 + (lane >> 4) * 4;
#pragma unroll
        for (int r = 0; r < 4; ++r) {
            float* Crow = Cp + (size_t)(grow + r) * 1024;
#pragma unroll
            for (int nf = 0; nf < 2; ++nf) {
                int gcol = col0 + wn * 32 + nf * 16 + (lane & 15);
                Crow[gcol] = acc[mf][nf][r] * scl + bv[nf];
            }
        }
    }
}

// ---------------------------------------------------------------------------
// FAVOR+ features via MFMA (phiK only): per block one bh, [128 t x 256 m].
// Unchanged (verified).
// ---------------------------------------------------------------------------
__global__ __launch_bounds__(256) void favor_mfma(const float* __restrict__ X,
                                                  const float* __restrict__ proj,
                                                  float* __restrict__ phi)
{
    const int bh = blockIdx.y;
    const int b = bh >> 4, h = bh & 15;
    const int t0 = blockIdx.x * 128;
    const int tid = threadIdx.x;
    const int w = tid >> 6, lane = tid & 63;

    __shared__ unsigned short Aq[128 * 136];   // [t][k'], hi 0..63, lo 64..127
    __shared__ unsigned short Bs[256 * 72];    // [m][k] hi only
    __shared__ float xns[128];

    const float* Xb = X + ((size_t)b * TT + t0) * DD + h * DK;
    const float* Pj = proj + (size_t)h * MM * DK;

#pragma unroll
    for (int i = 0; i < 8; i++) {
        int s = tid + i * 256;
        int r = s >> 4, q = (s & 15) * 4;
        float4 v = *(const float4*)(Xb + (size_t)r * DD + q);
        float f[4] = {v.x, v.y, v.z, v.w};
        union { _Float16 h[4]; uint2 u; } hv, lv;
#pragma unroll
        for (int e = 0; e < 4; e++) {
            hv.h[e] = (_Float16)f[e];
            lv.h[e] = (_Float16)(f[e] - (float)hv.h[e]);
        }
        *(uint2*)&Aq[r * 136 + q]      = hv.u;
        *(uint2*)&Aq[r * 136 + 64 + q] = lv.u;
    }
#pragma unroll
    for (int i = 0; i < 16; i++) {
        int s = tid + i * 256;
        int r = s >> 4, q = (s & 15) * 4;
        float4 v = *(const float4*)(Pj + (size_t)r * DK + q);
        float f[4] = {v.x, v.y, v.z, v.w};
        union { _Float16 h[4]; uint2 u; } hv;
#pragma unroll
        for (int e = 0; e < 4; e++) hv.h[e] = (_Float16)f[e];
        *(uint2*)&Bs[r * 72 + q] = hv.u;
    }
    __syncthreads();

    if (tid < 128) {
        const unsigned short* ar = &Aq[tid * 136];
        float s = 0.f;
#pragma unroll 8
        for (int k = 0; k < 64; k++) {
            float qv = (float)(*(const _Float16*)&ar[k])
                     + (float)(*(const _Float16*)&ar[64 + k]);
            s += qv * qv;
        }
        xns[tid] = s;
    }

    f32x4 acc[2][16];
#pragma unroll
    for (int i = 0; i < 2; i++)
#pragma unroll
        for (int j = 0; j < 16; j++) acc[i][j] = (f32x4){0.f, 0.f, 0.f, 0.f};

    const int arow0 = (w * 32 + (lane & 15)) * 136 + (lane >> 4) * 8;
    const int brow0 = (lane & 15) * 72 + (lane >> 4) * 8;
#pragma unroll
    for (int ks = 0; ks < 4; ks++) {
        f16x8 a0 = *(const f16x8*)&Aq[arow0 + ks * 32];
        f16x8 a1 = *(const f16x8*)&Aq[arow0 + 16 * 136 + ks * 32];
        const int bko = (ks & 1) * 32;
#pragma unroll
        for (int j = 0; j < 16; j++) {
            f16x8 bf = *(const f16x8*)&Bs[brow0 + j * 16 * 72 + bko];
            acc[0][j] = __builtin_amdgcn_mfma_f32_16x16x32_f16(a0, bf, acc[0][j], 0, 0, 0);
            acc[1][j] = __builtin_amdgcn_mfma_f32_16x16x32_f16(a1, bf, acc[1][j], 0, 0, 0);
        }
    }
    __syncthreads();

    float* outp = phi + ((size_t)bh * TT + t0) * MM;
#pragma unroll
    for (int i = 0; i < 2; i++) {
#pragma unroll
        for (int r = 0; r < 4; r++) {
            float mx = acc[i][0][r];
#pragma unroll
            for (int j = 1; j < 16; j++) mx = fmaxf(mx, acc[i][j][r]);
            mx = fmaxf(mx, __shfl_xor(mx, 1, 64));
            mx = fmaxf(mx, __shfl_xor(mx, 2, 64));
            mx = fmaxf(mx, __shfl_xor(mx, 4, 64));
            mx = fmaxf(mx, __shfl_xor(mx, 8, 64));
            const int row = w * 32 + i * 16 + (lane >> 4) * 4 + r;
            const float base = -mx - 0.5f * xns[row];
            float* orow = outp + (size_t)row * MM + (lane & 15);
#pragma unroll
            for (int j = 0; j < 16; j++)
                orow[j * 16] = (__expf(acc[i][j][r] + base) + FEPS) * 0.0625f;
        }
    }
}

// ---------------------------------------------------------------------------
// KV partial tiled GEMM: per block [64 m x 64 dk] over a 512-long t-chunk.
// (unchanged)
// ---------------------------------------------------------------------------
__global__ __launch_bounds__(256) void kv_partial(const float* __restrict__ phiK,
                                                  const float* __restrict__ V,
                                                  float* __restrict__ KVp)
{
    const int bh = blockIdx.y;
    const int b = bh >> 4, h = bh & 15;
    const int mt = blockIdx.x & 3;          // m-tile (64 wide)
    const int split = blockIdx.x >> 2;      // 0..7, 512 t each
    const int m0 = mt * 64;
    const int tid = threadIdx.x;
    const int tx = tid & 15;    // dk, 4 each
    const int ty = tid >> 4;    // m, 4 each

    __shared__ float Ps[32][68];
    __shared__ float Vs[32][68];

    float acc[4][4];
#pragma unroll
    for (int i = 0; i < 4; i++)
#pragma unroll
        for (int j = 0; j < 4; j++) acc[i][j] = 0.f;
    float ks0 = 0.f, ks1 = 0.f, ks2 = 0.f, ks3 = 0.f;

    const size_t pbase = (size_t)bh * TT * MM + m0;
    const size_t vbase = (size_t)b * TT * DD + h * DK;

    const int lt = tid >> 3;
    const int lc = (tid & 7) * 8;

    const int tend = split * 512 + 512;
    for (int t0 = split * 512; t0 < tend; t0 += 32) {
        const float* prow = phiK + pbase + (size_t)(t0 + lt) * MM + lc;
        const float* vrow = V + vbase + (size_t)(t0 + lt) * DD + lc;
        float4 p0 = *(const float4*)(prow);
        float4 p1 = *(const float4*)(prow + 4);
        float4 v0 = *(const float4*)(vrow);
        float4 v1 = *(const float4*)(vrow + 4);
        *(float4*)&Ps[lt][lc]     = p0;
        *(float4*)&Ps[lt][lc + 4] = p1;
        *(float4*)&Vs[lt][lc]     = v0;
        *(float4*)&Vs[lt][lc + 4] = v1;
        __syncthreads();
#pragma unroll
        for (int k = 0; k < 32; k++) {
            float4 a4 = *(const float4*)&Ps[k][ty * 4];
            float4 b4 = *(const float4*)&Vs[k][tx * 4];
            ks0 += a4.x; ks1 += a4.y; ks2 += a4.z; ks3 += a4.w;
            acc[0][0] += a4.x * b4.x; acc[0][1] += a4.x * b4.y;
            acc[0][2] += a4.x * b4.z; acc[0][3] += a4.x * b4.w;
            acc[1][0] += a4.y * b4.x; acc[1][1] += a4.y * b4.y;
            acc[1][2] += a4.y * b4.z; acc[1][3] += a4.y * b4.w;
            acc[2][0] += a4.z * b4.x; acc[2][1] += a4.z * b4.y;
            acc[2][2] += a4.z * b4.z; acc[2][3] += a4.z * b4.w;
            acc[3][0] += a4.w * b4.x; acc[3][1] += a4.w * b4.y;
            acc[3][2] += a4.w * b4.z; acc[3][3] += a4.w * b4.w;
        }
        __syncthreads();
    }

    float ksv[4] = {ks0, ks1, ks2, ks3};
    float* o = KVp + (((size_t)split * 32 + bh) * MM + m0) * 68;
#pragma unroll
    for (int i = 0; i < 4; i++) {
        float* orow = o + (size_t)(ty * 4 + i) * 68 + tx * 4;
        orow[0] = acc[i][0]; orow[1] = acc[i][1];
        orow[2] = acc[i][2]; orow[3] = acc[i][3];
        if (tx == 0) o[(size_t)(ty * 4 + i) * 68 + 64] = ksv[i];
    }
}

// ---------------------------------------------------------------------------
// kv_reduce v2: sum 8 split partials and emit KV^T directly as fp16 hi/lo
// planes: KVt16[bh][plane(2)][c(68)][m(256)], c: 0..63 = dk, 64 = Ksum.
// ---------------------------------------------------------------------------
__global__ __launch_bounds__(256) void kv_reduce(const float* __restrict__ KVp,
                                                 unsigned short* __restrict__ KVt16)
{
    int idx = blockIdx.x * 256 + threadIdx.x;   // 32*256*68 = 557056 exact
    float s = 0.f;
    for (int sp = 0; sp < 8; sp++) s += KVp[(size_t)sp * 32 * MM * 68 + idx];
    int bh = idx / 17408;
    int rm = idx - bh * 17408;
    int m = rm / 68;
    int c = rm - m * 68;
    _Float16 hv = (_Float16)0.f, lv = (_Float16)0.f;
    if (c <= 64) {
        hv = (_Float16)s;
        lv = (_Float16)(s - (float)hv);
    }
    KVt16[((size_t)(bh * 2 + 0) * 68 + c) * 256 + m] = f16bits(hv);
    KVt16[((size_t)(bh * 2 + 1) * 68 + c) * 256 + m] = f16bits(lv);
}

// ---------------------------------------------------------------------------
// FUSED favor(Q) + attn_out: per block one bh, 128 t rows. (unchanged)
// ---------------------------------------------------------------------------
__global__ __launch_bounds__(256, 2) void favor_attn(
    const float* __restrict__ X,
    const float* __restrict__ proj,
    const unsigned short* __restrict__ KVt16,
    unsigned short* __restrict__ mout)
{
    extern __shared__ char smem[];
    unsigned short* Xq = (unsigned short*)smem;             // [128][136]
    unsigned short* Pp = (unsigned short*)(smem + 34816);   // [256][72]
    float* xns         = (float*)(smem + 71680);            // [128]
    unsigned short* Aq = Xq;                                // phase B alias
    unsigned short* Bt = Pp;                                // [80][136]

    const int bh = blockIdx.y;
    const int b = bh >> 4, h = bh & 15;
    const int t0 = blockIdx.x * 128;
    const int tid = threadIdx.x;
    const int w = tid >> 6, lane = tid & 63;

    const float* Xb = X + ((size_t)b * TT + t0) * DD + h * DK;
    const float* Pj = proj + (size_t)h * MM * DK;

    // ---- phase A: stage X (hi/lo) + proj (hi) ----
#pragma unroll
    for (int i = 0; i < 8; i++) {
        int s = tid + i * 256;
        int r = s >> 4, q = (s & 15) * 4;
        float4 v = *(const float4*)(Xb + (size_t)r * DD + q);
        float f[4] = {v.x, v.y, v.z, v.w};
        union { _Float16 h[4]; uint2 u; } hv, lv;
#pragma unroll
        for (int e = 0; e < 4; e++) {
            hv.h[e] = (_Float16)f[e];
            lv.h[e] = (_Float16)(f[e] - (float)hv.h[e]);
        }
        *(uint2*)&Xq[r * 136 + q]      = hv.u;
        *(uint2*)&Xq[r * 136 + 64 + q] = lv.u;
    }
#pragma unroll
    for (int i = 0; i < 16; i++) {
        int s = tid + i * 256;
        int r = s >> 4, q = (s & 15) * 4;
        float4 v = *(const float4*)(Pj + (size_t)r * DK + q);
        float f[4] = {v.x, v.y, v.z, v.w};
        union { _Float16 h[4]; uint2 u; } hv;
#pragma unroll
        for (int e = 0; e < 4; e++) hv.h[e] = (_Float16)f[e];
        *(uint2*)&Pp[r * 72 + q] = hv.u;
    }
    __syncthreads();

    if (tid < 128) {
        const unsigned short* ar = &Xq[tid * 136];
        float s = 0.f;
#pragma unroll 8
        for (int k = 0; k < 64; k++) {
            float qv = (float)(*(const _Float16*)&ar[k])
                     + (float)(*(const _Float16*)&ar[64 + k]);
            s += qv * qv;
        }
        xns[tid] = s;
    }

    f32x4 facc[2][16];
#pragma unroll
    for (int i = 0; i < 2; i++)
#pragma unroll
        for (int j = 0; j < 16; j++) facc[i][j] = (f32x4){0.f, 0.f, 0.f, 0.f};

    const int arow0 = (w * 32 + (lane & 15)) * 136 + (lane >> 4) * 8;
    const int brow0 = (lane & 15) * 72 + (lane >> 4) * 8;
#pragma unroll
    for (int ks = 0; ks < 4; ks++) {
        f16x8 a0 = *(const f16x8*)&Xq[arow0 + ks * 32];
        f16x8 a1 = *(const f16x8*)&Xq[arow0 + 16 * 136 + ks * 32];
        const int bko = (ks & 1) * 32;
#pragma unroll
        for (int j = 0; j < 16; j++) {
            f16x8 bf = *(const f16x8*)&Pp[brow0 + j * 16 * 72 + bko];
            facc[0][j] = __builtin_amdgcn_mfma_f32_16x16x32_f16(a0, bf, facc[0][j], 0, 0, 0);
            facc[1][j] = __builtin_amdgcn_mfma_f32_16x16x32_f16(a1, bf, facc[1][j], 0, 0, 0);
        }
    }
    __syncthreads();   // phase A LDS reads done; xns visible

    // rowmax -> base per (i, r)
    float base[2][4];
#pragma unroll
    for (int i = 0; i < 2; i++) {
#pragma unroll
        for (int r = 0; r < 4; r++) {
            float mx = facc[i][0][r];
#pragma unroll
            for (int j = 1; j < 16; j++) mx = fmaxf(mx, facc[i][j][r]);
            mx = fmaxf(mx, __shfl_xor(mx, 1, 64));
            mx = fmaxf(mx, __shfl_xor(mx, 2, 64));
            mx = fmaxf(mx, __shfl_xor(mx, 4, 64));
            mx = fmaxf(mx, __shfl_xor(mx, 8, 64));
            const int row = w * 32 + i * 16 + (lane >> 4) * 4 + r;
            base[i][r] = -mx - 0.5f * xns[row];
        }
    }

    // ---- phase B: chunked phi->Aq + KV^T->Bt + 3-seg MFMA ----
    f32x4 aacc[2][5];
#pragma unroll
    for (int i = 0; i < 2; i++)
#pragma unroll
        for (int j = 0; j < 5; j++) aacc[i][j] = (f32x4){0.f, 0.f, 0.f, 0.f};

    const int aFr = (w * 32 + (lane & 15)) * 136 + (lane >> 4) * 8;
    const int bFr = (lane & 15) * 136 + (lane >> 4) * 8;

#pragma unroll
    for (int c = 0; c < 4; c++) {
        // write phi chunk (hi|lo) to Aq in A-layout [t][mc]
#pragma unroll
        for (int i = 0; i < 2; i++) {
#pragma unroll
            for (int jj = 0; jj < 4; jj++) {
#pragma unroll
                for (int r = 0; r < 4; r++) {
                    float ph = (__expf(facc[i][c * 4 + jj][r] + base[i][r]) + FEPS) * 0.0625f;
                    _Float16 hv = (_Float16)ph;
                    _Float16 lv = (_Float16)(ph - (float)hv);
                    int row = w * 32 + i * 16 + (lane >> 4) * 4 + r;
                    int mc = jj * 16 + (lane & 15);
                    Aq[row * 136 + mc]      = f16bits(hv);
                    Aq[row * 136 + 64 + mc] = f16bits(lv);
                }
            }
        }
        // stage Bt chunk: rows 0..67 from KVt16, 68..79 zero
#pragma unroll
        for (int i = 0; i < 10; i++) {
            int s = tid + i * 256;           // 2560 = 2 planes * 80 rows * 16 quads
            int p = (s >= 1280) ? 1 : 0;
            int s2 = s - p * 1280;
            int r = s2 >> 4, q = (s2 & 15) * 4;
            uint2 v = make_uint2(0u, 0u);
            if (r < 68)
                v = *(const uint2*)(KVt16 + ((size_t)(bh * 2 + p) * 68 + r) * 256 + c * 64 + q);
            *(uint2*)&Bt[r * 136 + p * 64 + q] = v;
        }
        __syncthreads();
#pragma unroll
        for (int ks = 0; ks < 2; ks++) {
            f16x8 ah0 = *(const f16x8*)&Aq[aFr + ks * 32];
            f16x8 ah1 = *(const f16x8*)&Aq[aFr + 16 * 136 + ks * 32];
            f16x8 al0 = *(const f16x8*)&Aq[aFr + 64 + ks * 32];
            f16x8 al1 = *(const f16x8*)&Aq[aFr + 16 * 136 + 64 + ks * 32];
#pragma unroll
            for (int j = 0; j < 5; j++) {
                f16x8 bh_ = *(const f16x8*)&Bt[bFr + j * 16 * 136 + ks * 32];
                f16x8 bl_ = *(const f16x8*)&Bt[bFr + j * 16 * 136 + 64 + ks * 32];
                aacc[0][j] = __builtin_amdgcn_mfma_f32_16x16x32_f16(ah0, bl_, aacc[0][j], 0, 0, 0);
                aacc[0][j] = __builtin_amdgcn_mfma_f32_16x16x32_f16(al0, bh_, aacc[0][j], 0, 0, 0);
                aacc[0][j] = __builtin_amdgcn_mfma_f32_16x16x32_f16(ah0, bh_, aacc[0][j], 0, 0, 0);
                aacc[1][j] = __builtin_amdgcn_mfma_f32_16x16x32_f16(ah1, bl_, aacc[1][j], 0, 0, 0);
                aacc[1][j] = __builtin_amdgcn_mfma_f32_16x16x32_f16(al1, bh_, aacc[1][j], 0, 0, 0);
                aacc[1][j] = __builtin_amdgcn_mfma_f32_16x16x32_f16(ah1, bh_, aacc[1][j], 0, 0, 0);
            }
        }
        __syncthreads();
    }

    // ---- epilogue: out = num/(den+eps), write merged fp16 hi/lo ----
    unsigned short* Mh = mout + ((size_t)b * TT + t0) * 2048 + h * DK;
#pragma unroll
    for (int i = 0; i < 2; i++) {
#pragma unroll
        for (int r = 0; r < 4; r++) {
            float den = aacc[i][4][r];                 // col 64 lives at lane&15==0
            den = __shfl(den, lane & 48, 64);          // broadcast to the 16-lane group
            float dinv = 1.f / (den + FEPS);
            int trow = w * 32 + i * 16 + (lane >> 4) * 4 + r;
#pragma unroll
            for (int j = 0; j < 4; j++) {
                float o = aacc[i][j][r] * dinv;
                _Float16 hv = (_Float16)o;
                _Float16 lv = (_Float16)(o - (float)hv);
                Mh[(size_t)trow * 2048 + j * 16 + (lane & 15)]        = f16bits(hv);
                Mh[(size_t)trow * 2048 + 1024 + j * 16 + (lane & 15)] = f16bits(lv);
            }
        }
    }
}

// ---------------------------------------------------------------------------
extern "C" void kernel_launch(void* const* d_in, const int* in_sizes, int n_in,
                              void* d_out, int out_size, void* d_ws, size_t ws_size,
                              hipStream_t stream)
{
    (void)in_sizes; (void)n_in; (void)out_size; (void)ws_size;
    const float* x    = (const float*)d_in[0];
    const float* Wq   = (const float*)d_in[1];
    const float* Wk   = (const float*)d_in[2];
    const float* Wv   = (const float*)d_in[3];
    const float* Wo   = (const float*)d_in[4];
    const float* bo   = (const float*)d_in[5];
    const float* proj = (const float*)d_in[6];
    float* out = (float*)d_out;

    float* ws  = (float*)d_ws;
    float* Qs  = ws;                          // 8388608 floats
    float* Ks  = Qs + 8388608ull;             // 8388608
    float* Vb  = Ks + 8388608ull;             // 8388608
    float* phi = Vb + 8388608ull;             // 33554432 (phiK only)
    float* KVp = phi + 33554432ull;           // 8*32*256*68 = 4456448

    // aliases (lifetime-disjoint with their hosts):
    unsigned short* x_hl  = (unsigned short*)phi;  // dead once favor writes phi
    unsigned short* wqkv  = (unsigned short*)KVp;  // dead before kv_partial writes
    unsigned short* wo_h  = (unsigned short*)Qs;   // written after Qs is dead
    unsigned short* m_hl  = (unsigned short*)Ks;   // written after Ks is dead
    unsigned short* KVt16 = (unsigned short*)phi;  // written after phiK is dead

    dim3 gthr(256);

    split_w3h<<<dim3(3072), gthr, 0, stream>>>(Wq, Wk, Wv, wqkv);
    split_hl <<<dim3(8192), gthr, 0, stream>>>(x, x_hl);
    // QKV projection: 768 blocks = 3 full 256-CU rounds at 1 block/CU
    gemm_pipe<<<dim3(24, 32), dim3(512), 98304, stream>>>(
        x_hl, wqkv, wqkv + 1048576, wqkv + 2097152,
        Qs, Ks, Vb, nullptr, 0.125f, 0.125f, 1.0f);

    favor_mfma<<<dim3(32, 32), gthr, 0, stream>>>(Ks, proj, phi);      // phiK (clobbers x_hl, dead)
    kv_partial<<<dim3(32, 32), gthr, 0, stream>>>(phi, Vb, KVp);       // clobbers wqkv (dead)
    kv_reduce <<<dim3(2176),   gthr, 0, stream>>>(KVp, KVt16);         // KVt16 over dead phiK
    favor_attn<<<dim3(32, 32), gthr, 72192, stream>>>(Qs, proj, KVt16, m_hl);  // Qs dead after
    split_w3h <<<dim3(1024),   gthr, 0, stream>>>(Wo, Wo, Wo, wo_h);   // into Qs region

    // out projection: 256 blocks = exactly 1 full round
    gemm_pipe<<<dim3(8, 32), dim3(512), 98304, stream>>>(
        m_hl, wo_h, wo_h, wo_h, out, out, out, bo, 1.0f, 1.0f, 1.0f);
}